// Round 8
// baseline (10590.765 us; speedup 1.0000x reference)
//
#include <hip/hip_runtime.h>
#include <hip/hip_bf16.h>
#include <stdint.h>

// Neural CDE, B=256 T=512 D=64 H=128 W=256.
// Round 8: r3 topology (8 groups x 32 WGs, redundant stage A, tagged bf16 push
// exchange) restructured for minimum phase overhead:
//  - 3 barriers/step (was 6): yb double-buffered, g0/g1 separate, pbuf deleted.
//  - gemm2 direct-publish layout: wave wv owns h = 4j+(wv&3), rows (wv>>2)*16..+15,
//    all 64 d in-reg (c=0..3) -> 2 shuffles, publish straight from the wave.
//  - w0/w1 fragments + biases VGPR-resident via amdgpu_num_vgpr(224); w2 streamed.
//  - deriv as direct f32x4 global loads (no dv LDS).
// dt = 1, frac = 0 for k<=510 => deriv = coeffs_b[:,k]; k=511 => b+2c+3d at idx 510.

#define BB 256
#define DD 64
#define HH 128
#define WW 256
#define HD 8192
#define TSTEPS 512
#define PAD_Y 136   // bf16 row stride (272 B -> 2-way bank alias, free)
#define PAD_G 264   // bf16 row stride (528 B -> 2-way, free)

typedef __bf16 bf16x8 __attribute__((ext_vector_type(8)));
typedef __bf16 bf16x4 __attribute__((ext_vector_type(4)));
typedef float f32x4 __attribute__((ext_vector_type(4)));

__device__ __forceinline__ float softplus_f(float x) {
  return (x > 15.f) ? x : __logf(1.f + __expf(x));
}
__device__ __forceinline__ float tanh_f(float x) {
  float e = __expf(2.f * x);
  return 1.f - 2.f / (e + 1.f);
}
__device__ __forceinline__ uint32_t aload(const uint32_t* p) {
  return __hip_atomic_load(p, __ATOMIC_RELAXED, __HIP_MEMORY_SCOPE_AGENT);
}
__device__ __forceinline__ void publish_y(uint32_t* slot, int idx, float val, uint32_t tag) {
  unsigned short ub = __builtin_bit_cast(unsigned short, (__bf16)val);
  __hip_atomic_store(&slot[idx], (tag << 16) | (uint32_t)ub,
                     __ATOMIC_RELAXED, __HIP_MEMORY_SCOPE_AGENT);
}

__global__ void prep_kernel(const float* __restrict__ w0, const float* __restrict__ w1,
                            const float* __restrict__ w2,
                            __bf16* __restrict__ w0b, __bf16* __restrict__ w1b,
                            __bf16* __restrict__ w2b) {
  int stride = gridDim.x * blockDim.x;
  int i0 = blockIdx.x * blockDim.x + threadIdx.x;
  for (int i = i0; i < WW * HH; i += stride) w0b[i] = (__bf16)w0[i];
  for (int i = i0; i < WW * WW; i += stride) w1b[i] = (__bf16)w1[i];
  for (int i = i0; i < HD * WW; i += stride) w2b[i] = (__bf16)w2[i];
}

__global__ __launch_bounds__(256) void init_kernel(
    const float* __restrict__ ca, const float* __restrict__ iw0, const float* __restrict__ ib0,
    const float* __restrict__ iw1, const float* __restrict__ ib1,
    const float* __restrict__ iw2, const float* __restrict__ ib2,
    float* __restrict__ y0) {
  __shared__ float x0[DD];
  __shared__ float h0[WW];
  __shared__ float h1[WW];
  int b = blockIdx.x, t = threadIdx.x;
  if (t < DD) x0[t] = ca[((size_t)b * 511) * DD + t];
  __syncthreads();
  float a = ib0[t];
  for (int d = 0; d < DD; ++d) a = fmaf(x0[d], iw0[t * DD + d], a);
  h0[t] = fmaxf(a, 0.f);
  __syncthreads();
  a = ib1[t];
  for (int d = 0; d < WW; ++d) a = fmaf(h0[d], iw1[t * WW + d], a);
  h1[t] = fmaxf(a, 0.f);
  __syncthreads();
  if (t < HH) {
    a = ib2[t];
    for (int d = 0; d < WW; ++d) a = fmaf(h1[d], iw2[t * WW + d], a);
    y0[b * HH + t] = a;
  }
}

// Persistent step kernel: 256 WGs x 512 threads, loops k=0..511 internally.
__global__ __attribute__((amdgpu_flat_work_group_size(512, 512), amdgpu_waves_per_eu(2, 2)))
#if __has_attribute(amdgpu_num_vgpr)
__attribute__((amdgpu_num_vgpr(224)))
#endif
void step_persist(
    const __bf16* __restrict__ w0b, const __bf16* __restrict__ w1b, const __bf16* __restrict__ w2b,
    const float* __restrict__ fb0, const float* __restrict__ fb1, const float* __restrict__ fb2,
    const float* __restrict__ cbp, const float* __restrict__ ccp, const float* __restrict__ cdp,
    float* __restrict__ yA, uint32_t* __restrict__ pk)
{
  __shared__ __align__(16) __bf16 yb[2][32 * PAD_Y];
  __shared__ __align__(16) __bf16 g0s[32 * PAD_G];
  __shared__ __align__(16) __bf16 g1s[32 * PAD_G];

  const int tid = threadIdx.x;
  const int wv = tid >> 6;
  const int l = tid & 63;
  const int l16 = l & 15;
  const int lq = l >> 4;

  const int wid = blockIdx.x;
  const int grp = wid >> 5;
  const int j = wid & 31;
  const int rb = grp * 32;     // batch row base
  const int c0 = j * 256;      // HD col base
  const int rt = wv >> 2;      // gemm2/publish row-tile (16 rows)
  const int hq = wv & 3;       // gemm2/publish h-quadrant

  // ---- loop-invariant, intended VGPR-resident: w0 (32 VGPR) + w1 (64 VGPR) frags
  bf16x8 w0f[4][2], w1f[8][2];
  f32x4 b0r[2], b1r[2];
  #pragma unroll
  for (int cc = 0; cc < 2; ++cc) {
    int colA = wv * 32 + cc * 16 + l16;
    #pragma unroll
    for (int kb = 0; kb < 4; ++kb)
      w0f[kb][cc] = *(const bf16x8*)&w0b[colA * HH + kb * 32 + lq * 8];
    #pragma unroll
    for (int kb = 0; kb < 8; ++kb)
      w1f[kb][cc] = *(const bf16x8*)&w1b[colA * WW + kb * 32 + lq * 8];
    b0r[cc] = *(const f32x4*)&fb0[wv * 32 + cc * 16 + lq * 4];
    b1r[cc] = *(const f32x4*)&fb1[wv * 32 + cc * 16 + lq * 4];
  }
  // gemm2 bias, c4 layout over this wave's h-quadrant
  f32x4 b2r[4];
  #pragma unroll
  for (int c = 0; c < 4; ++c)
    b2r[c] = *(const f32x4*)&fb2[c0 + hq * 64 + c * 16 + lq * 4];

  // ---- deriv base: row = rb + rt*16 + l16, d = c*16 + lq*4 (+r)
  const size_t dvbase = ((size_t)(rb + rt * 16 + l16) * 511) * DD + lq * 4;

  // ---- register-resident f32 state: wave wv lane l<16 owns (row rb+rt*16+l, h=4j+hq)
  const int myidx = (rb + rt * 16 + l16) * HH + (4 * j + hq);
  float yreg = 0.f;
  if (l < 16) {
    yreg = yA[myidx];
    publish_y(pk, myidx, yreg, 1u);   // S_0 -> slot 0, tag 1
  }

  for (int k = 0; k < TSTEPS; ++k) {
    const uint32_t want = (uint32_t)(k + 1);
    const uint32_t* src = pk + (size_t)(k & 1) * (BB * HH);
    __bf16* ybk = yb[k & 1];

    // ---- deriv loads (independent; consumed in gemm2)
    f32x4 dvv[4];
    {
      size_t ko = dvbase + (size_t)((k <= 510) ? k : 510) * DD;
      #pragma unroll
      for (int c = 0; c < 4; ++c) dvv[c] = *(const f32x4*)&cbp[ko + c * 16];
      if (k == 511) {
        #pragma unroll
        for (int c = 0; c < 4; ++c) {
          f32x4 cc = *(const f32x4*)&ccp[ko + c * 16];
          f32x4 dd = *(const f32x4*)&cdp[ko + c * 16];
          #pragma unroll
          for (int r = 0; r < 4; ++r) dvv[c][r] += 2.f * cc[r] + 3.f * dd[r];
        }
      }
    }

    // ---- poll + stage peers' y (tagged bf16 words) into yb[k&1]
    {
      uint32_t v[8];
      int ad[8];
      #pragma unroll
      for (int q = 0; q < 8; ++q) {
        int i = tid + q * 512;
        ad[q] = (rb + (i >> 7)) * HH + (i & 127);
        v[q] = aload(&src[ad[q]]);
      }
      int spins = 0;
      bool allok;
      do {
        allok = true;
        #pragma unroll
        for (int q = 0; q < 8; ++q) {
          if ((v[q] >> 16) != want) {
            allok = false;
            v[q] = aload(&src[ad[q]]);
          }
        }
        if (!allok) {
          __builtin_amdgcn_s_sleep(1);
          if (++spins > (1 << 20)) break;   // structurally impossible; bail visibly
        }
      } while (!allok);
      #pragma unroll
      for (int q = 0; q < 8; ++q) {
        int i = tid + q * 512;
        ybk[(i >> 7) * PAD_Y + (i & 127)] =
            __builtin_bit_cast(__bf16, (unsigned short)(v[q] & 0xFFFFu));
      }
    }
    __syncthreads();   // 1: yb ready

    // ---- gemm0 (swapped, c2 layout): D[w0col, brow] = w0 . y
    {
      f32x4 acc[2][2] = {};
      #pragma unroll
      for (int kb = 0; kb < 4; ++kb) {
        bf16x8 y0 = *(const bf16x8*)&ybk[l16 * PAD_Y + kb * 32 + lq * 8];
        bf16x8 y1 = *(const bf16x8*)&ybk[(16 + l16) * PAD_Y + kb * 32 + lq * 8];
        #pragma unroll
        for (int cc = 0; cc < 2; ++cc) {
          acc[cc][0] = __builtin_amdgcn_mfma_f32_16x16x32_bf16(w0f[kb][cc], y0, acc[cc][0], 0, 0, 0);
          acc[cc][1] = __builtin_amdgcn_mfma_f32_16x16x32_bf16(w0f[kb][cc], y1, acc[cc][1], 0, 0, 0);
        }
      }
      #pragma unroll
      for (int cc = 0; cc < 2; ++cc)
        #pragma unroll
        for (int bt = 0; bt < 2; ++bt) {
          bf16x4 o;
          #pragma unroll
          for (int r = 0; r < 4; ++r)
            o[r] = (__bf16)softplus_f(acc[cc][bt][r] + b0r[cc][r]);
          *(bf16x4*)&g0s[(bt * 16 + l16) * PAD_G + wv * 32 + cc * 16 + lq * 4] = o;
        }
    }
    __syncthreads();   // 2: g0 ready

    // ---- gemm1 (swapped, c2 layout): reads g0, writes g1
    {
      f32x4 acc[2][2] = {};
      #pragma unroll
      for (int kb = 0; kb < 8; ++kb) {
        bf16x8 a0 = *(const bf16x8*)&g0s[l16 * PAD_G + kb * 32 + lq * 8];
        bf16x8 a1 = *(const bf16x8*)&g0s[(16 + l16) * PAD_G + kb * 32 + lq * 8];
        #pragma unroll
        for (int cc = 0; cc < 2; ++cc) {
          acc[cc][0] = __builtin_amdgcn_mfma_f32_16x16x32_bf16(w1f[kb][cc], a0, acc[cc][0], 0, 0, 0);
          acc[cc][1] = __builtin_amdgcn_mfma_f32_16x16x32_bf16(w1f[kb][cc], a1, acc[cc][1], 0, 0, 0);
        }
      }
      #pragma unroll
      for (int cc = 0; cc < 2; ++cc)
        #pragma unroll
        for (int bt = 0; bt < 2; ++bt) {
          bf16x4 o;
          #pragma unroll
          for (int r = 0; r < 4; ++r)
            o[r] = (__bf16)softplus_f(acc[cc][bt][r] + b1r[cc][r]);
          *(bf16x4*)&g1s[(bt * 16 + l16) * PAD_G + wv * 32 + cc * 16 + lq * 4] = o;
        }
    }
    __syncthreads();   // 3: g1 ready

    // ---- gemm2, direct-publish layout: wave owns h=4j+hq, rows rt*16..+15,
    //      cols (c4 over all 64 d). w2 streamed from L2 per step.
    {
      f32x4 acc[4] = {};
      #pragma unroll
      for (int kb = 0; kb < 8; ++kb) {
        bf16x8 a0 = *(const bf16x8*)&g1s[(rt * 16 + l16) * PAD_G + kb * 32 + lq * 8];
        #pragma unroll
        for (int c = 0; c < 4; ++c) {
          bf16x8 wf = *(const bf16x8*)&w2b[(size_t)(c0 + hq * 64 + c * 16 + l16) * WW +
                                           kb * 32 + lq * 8];
          acc[c] = __builtin_amdgcn_mfma_f32_16x16x32_bf16(wf, a0, acc[c], 0, 0, 0);
        }
      }
      // lane: batch row = rt*16+l16; d = c*16 + lq*4 + r (all 64 d in this wave)
      float pp = 0.f;
      #pragma unroll
      for (int c = 0; c < 4; ++c)
        #pragma unroll
        for (int r = 0; r < 4; ++r) {
          float f = tanh_f(acc[c][r] + b2r[c][r]);
          pp = fmaf(f, dvv[c][r], pp);
        }
      pp += __shfl_xor(pp, 16);
      pp += __shfl_xor(pp, 32);
      // ---- update register state + publish (no barrier, no pbuf)
      if (l < 16) {
        yreg += pp;
        publish_y(pk + (size_t)((k + 1) & 1) * (BB * HH), myidx, yreg, (uint32_t)(k + 2));
      }
    }
    // no trailing barrier: yb double-buffered; g0/g1 WAR protected by barriers 1-2
    // of the next iteration (all threads must pass them before overwriting).
  }

  if (l < 16) yA[myidx] = yreg;
}

__global__ __launch_bounds__(256) void final_kernel(const float* __restrict__ y,
                                                    const float* __restrict__ lw,
                                                    const float* __restrict__ lb,
                                                    float* __restrict__ out) {
  int b = threadIdx.x;
  float a = lb[0];
  for (int h = 0; h < HH; ++h) a = fmaf(y[b * HH + h], lw[h], a);
  out[b] = 1.f / (1.f + __expf(-a));
}

extern "C" void kernel_launch(void* const* d_in, const int* in_sizes, int n_in,
                              void* d_out, int out_size, void* d_ws, size_t ws_size,
                              hipStream_t stream) {
  const float* cdp = (const float*)d_in[1];
  const float* ccp = (const float*)d_in[2];
  const float* cbp = (const float*)d_in[3];
  const float* cap = (const float*)d_in[4];
  const float* iw0 = (const float*)d_in[5];
  const float* ib0 = (const float*)d_in[6];
  const float* iw1 = (const float*)d_in[7];
  const float* ib1 = (const float*)d_in[8];
  const float* iw2 = (const float*)d_in[9];
  const float* ib2 = (const float*)d_in[10];
  const float* fw0 = (const float*)d_in[11];
  const float* fb0 = (const float*)d_in[12];
  const float* fw1 = (const float*)d_in[13];
  const float* fb1 = (const float*)d_in[14];
  const float* fw2 = (const float*)d_in[15];
  const float* fb2 = (const float*)d_in[16];
  const float* lw  = (const float*)d_in[17];
  const float* lb  = (const float*)d_in[18];

  char* ws = (char*)d_ws;
  __bf16* w0b = (__bf16*)(ws);                              // 64 KB
  __bf16* w1b = (__bf16*)(ws + 65536);                      // 128 KB
  __bf16* w2b = (__bf16*)(ws + 65536 + 131072);             // 4 MB
  float* yA = (float*)(ws + 65536 + 131072 + 4194304);      // 128 KB
  uint32_t* pk = (uint32_t*)(ws + 65536 + 131072 + 4194304 + 131072);  // 256 KB (2 slots)

  hipMemsetAsync(pk, 0, 2 * BB * HH * sizeof(uint32_t), stream);
  prep_kernel<<<512, 256, 0, stream>>>(fw0, fw1, fw2, w0b, w1b, w2b);
  init_kernel<<<BB, 256, 0, stream>>>(cap, iw0, ib0, iw1, ib1, iw2, ib2, yA);
  step_persist<<<256, 512, 0, stream>>>(w0b, w1b, w2b, fb0, fb1, fb2,
                                        cbp, ccp, cdp, yA, pk);
  final_kernel<<<1, 256, 0, stream>>>(yA, lw, lb, (float*)d_out);

  (void)in_sizes; (void)n_in; (void)out_size; (void)ws_size;
}

// Round 9
// 7102.968 us; speedup vs baseline: 1.4910x; 1.4910x over previous
//
#include <hip/hip_runtime.h>
#include <hip/hip_bf16.h>
#include <stdint.h>

// Neural CDE, B=256 T=512 D=64 H=128 W=256.
// Round 9: 16 groups x 16 rows, 16 WGs/group x 512 HD-cols, 3 barriers/step.
//  - stage-A redundancy halved (16x on 16-row tiles); per-wave full-h gemm2
//    -> direct publish (no pbuf/combine); poll 4 words/thread.
//  - r3's proven tagged bf16 push-exchange (2-slot, ABA-safe, relaxed agent atomics).
//  - weights streamed r3-style (<=2 frags/kb, ds-frags hoisted); VGPR cap 128.
// dt = 1, frac = 0 for k<=510 => deriv = coeffs_b[:,k]; k=511 => b+2c+3d at idx 510.

#define BB 256
#define DD 64
#define HH 128
#define WW 256
#define HD 8192
#define TSTEPS 512
#define NGRP 16
#define GR 16        // rows per group
#define CW 512       // HD cols per WG
#define PAD_Y 136    // bf16 row stride for yb
#define PAD_G 264    // bf16 row stride for g0/g1

typedef __bf16 bf16x8 __attribute__((ext_vector_type(8)));
typedef __bf16 bf16x4 __attribute__((ext_vector_type(4)));
typedef float f32x4 __attribute__((ext_vector_type(4)));

__device__ __forceinline__ float softplus_f(float x) {
  return (x > 15.f) ? x : __logf(1.f + __expf(x));
}
__device__ __forceinline__ float tanh_f(float x) {
  float e = __expf(2.f * x);
  return 1.f - 2.f / (e + 1.f);
}
__device__ __forceinline__ uint32_t aload(const uint32_t* p) {
  return __hip_atomic_load(p, __ATOMIC_RELAXED, __HIP_MEMORY_SCOPE_AGENT);
}
__device__ __forceinline__ void publish_y(uint32_t* slot, int idx, float val, uint32_t tag) {
  unsigned short ub = __builtin_bit_cast(unsigned short, (__bf16)val);
  __hip_atomic_store(&slot[idx], (tag << 16) | (uint32_t)ub,
                     __ATOMIC_RELAXED, __HIP_MEMORY_SCOPE_AGENT);
}

__global__ void prep_kernel(const float* __restrict__ w0, const float* __restrict__ w1,
                            const float* __restrict__ w2,
                            __bf16* __restrict__ w0b, __bf16* __restrict__ w1b,
                            __bf16* __restrict__ w2b) {
  int stride = gridDim.x * blockDim.x;
  int i0 = blockIdx.x * blockDim.x + threadIdx.x;
  for (int i = i0; i < WW * HH; i += stride) w0b[i] = (__bf16)w0[i];
  for (int i = i0; i < WW * WW; i += stride) w1b[i] = (__bf16)w1[i];
  for (int i = i0; i < HD * WW; i += stride) w2b[i] = (__bf16)w2[i];
}

__global__ __launch_bounds__(256) void init_kernel(
    const float* __restrict__ ca, const float* __restrict__ iw0, const float* __restrict__ ib0,
    const float* __restrict__ iw1, const float* __restrict__ ib1,
    const float* __restrict__ iw2, const float* __restrict__ ib2,
    float* __restrict__ y0) {
  __shared__ float x0[DD];
  __shared__ float h0[WW];
  __shared__ float h1[WW];
  int b = blockIdx.x, t = threadIdx.x;
  if (t < DD) x0[t] = ca[((size_t)b * 511) * DD + t];
  __syncthreads();
  float a = ib0[t];
  for (int d = 0; d < DD; ++d) a = fmaf(x0[d], iw0[t * DD + d], a);
  h0[t] = fmaxf(a, 0.f);
  __syncthreads();
  a = ib1[t];
  for (int d = 0; d < WW; ++d) a = fmaf(h0[d], iw1[t * WW + d], a);
  h1[t] = fmaxf(a, 0.f);
  __syncthreads();
  if (t < HH) {
    a = ib2[t];
    for (int d = 0; d < WW; ++d) a = fmaf(h1[d], iw2[t * WW + d], a);
    y0[b * HH + t] = a;
  }
}

// Persistent step kernel: 256 WGs x 512 threads, loops k=0..511 internally.
__global__ __launch_bounds__(512, 2) void step_persist(
    const __bf16* __restrict__ w0b, const __bf16* __restrict__ w1b, const __bf16* __restrict__ w2b,
    const float* __restrict__ fb0, const float* __restrict__ fb1, const float* __restrict__ fb2,
    const float* __restrict__ cbp, const float* __restrict__ ccp, const float* __restrict__ cdp,
    float* __restrict__ yA, uint32_t* __restrict__ pk)
{
  __shared__ __align__(16) __bf16 yb[GR * PAD_Y];
  __shared__ __align__(16) __bf16 g0s[GR * PAD_G];
  __shared__ __align__(16) __bf16 g1s[GR * PAD_G];

  const int tid = threadIdx.x;
  const int wv = tid >> 6;
  const int l = tid & 63;
  const int l16 = l & 15;
  const int lq = l >> 4;

  const int wid = blockIdx.x;
  const int grp = wid >> 4;     // 16 groups
  const int j = wid & 15;       // 16 WGs per group
  const int rb = grp * GR;      // batch row base (16 rows)
  const int c0 = j * CW;        // HD col base (512 cols = 8 h)

  // biases (col-quad layout, reg dim)
  f32x4 b0r[2], b1r[2], b2r[4];
  #pragma unroll
  for (int cc = 0; cc < 2; ++cc) {
    b0r[cc] = *(const f32x4*)&fb0[wv * 32 + cc * 16 + lq * 4];
    b1r[cc] = *(const f32x4*)&fb1[wv * 32 + cc * 16 + lq * 4];
  }
  #pragma unroll
  for (int c = 0; c < 4; ++c)
    b2r[c] = *(const f32x4*)&fb2[c0 + wv * 64 + c * 16 + lq * 4];

  // deriv base: row = rb + l16, d = c*16 + lq*4 (+r)
  const size_t dvbase = ((size_t)(rb + l16) * 511) * DD + lq * 4;

  // register-resident f32 state: lane l<16 of wave wv owns (row rb+l16, h=8j+wv)
  const int myidx = (rb + l16) * HH + (8 * j + wv);
  float yreg = 0.f;
  if (l < 16) {
    yreg = yA[myidx];
    publish_y(pk, myidx, yreg, 1u);   // S_0 -> slot 0, tag 1
  }

  for (int k = 0; k < TSTEPS; ++k) {
    const uint32_t want = (uint32_t)(k + 1);
    const uint32_t* src = pk + (size_t)(k & 1) * (BB * HH);
    uint32_t* dst = pk + (size_t)((k + 1) & 1) * (BB * HH);

    // ---- deriv loads (consumed in gemm2; latency hidden under gemm0/1)
    f32x4 dvv[4];
    {
      size_t ko = dvbase + (size_t)((k <= 510) ? k : 510) * DD;
      #pragma unroll
      for (int c = 0; c < 4; ++c) dvv[c] = *(const f32x4*)&cbp[ko + c * 16];
      if (k == 511) {
        #pragma unroll
        for (int c = 0; c < 4; ++c) {
          f32x4 cc = *(const f32x4*)&ccp[ko + c * 16];
          f32x4 dd = *(const f32x4*)&cdp[ko + c * 16];
          #pragma unroll
          for (int r = 0; r < 4; ++r) dvv[c][r] += 2.f * cc[r] + 3.f * dd[r];
        }
      }
    }

    // ---- poll this group's 16x128 y words (4 per thread), stage to yb
    {
      uint32_t v[4];
      int ad[4];
      #pragma unroll
      for (int q = 0; q < 4; ++q) {
        int i = tid + q * 512;
        ad[q] = (rb + (i >> 7)) * HH + (i & 127);
        v[q] = aload(&src[ad[q]]);
      }
      int spins = 0;
      bool allok;
      do {
        allok = true;
        #pragma unroll
        for (int q = 0; q < 4; ++q) {
          if ((v[q] >> 16) != want) {
            allok = false;
            v[q] = aload(&src[ad[q]]);
          }
        }
        if (!allok) {
          __builtin_amdgcn_s_sleep(1);
          if (++spins > (1 << 20)) break;   // structurally impossible; bail visibly
        }
      } while (!allok);
      #pragma unroll
      for (int q = 0; q < 4; ++q) {
        int i = tid + q * 512;
        yb[(i >> 7) * PAD_Y + (i & 127)] =
            __builtin_bit_cast(__bf16, (unsigned short)(v[q] & 0xFFFFu));
      }
    }
    __syncthreads();   // 1: yb ready

    // ---- gemm0 (swapped, c2): D[w0col, brow] = w0 . y  (16 rows, bt=0 only)
    {
      bf16x8 yf[4];
      #pragma unroll
      for (int kb = 0; kb < 4; ++kb)
        yf[kb] = *(const bf16x8*)&yb[l16 * PAD_Y + kb * 32 + lq * 8];
      f32x4 acc[2] = {};
      #pragma unroll
      for (int kb = 0; kb < 4; ++kb) {
        #pragma unroll
        for (int cc = 0; cc < 2; ++cc) {
          bf16x8 wf = *(const bf16x8*)&w0b[(wv * 32 + cc * 16 + l16) * HH + kb * 32 + lq * 8];
          acc[cc] = __builtin_amdgcn_mfma_f32_16x16x32_bf16(wf, yf[kb], acc[cc], 0, 0, 0);
        }
      }
      #pragma unroll
      for (int cc = 0; cc < 2; ++cc) {
        bf16x4 o;
        #pragma unroll
        for (int r = 0; r < 4; ++r)
          o[r] = (__bf16)softplus_f(acc[cc][r] + b0r[cc][r]);
        *(bf16x4*)&g0s[l16 * PAD_G + wv * 32 + cc * 16 + lq * 4] = o;
      }
    }
    __syncthreads();   // 2: g0 ready

    // ---- gemm1 (swapped, c2): reads g0, writes g1
    {
      bf16x8 af[8];
      #pragma unroll
      for (int kb = 0; kb < 8; ++kb)
        af[kb] = *(const bf16x8*)&g0s[l16 * PAD_G + kb * 32 + lq * 8];
      f32x4 acc[2] = {};
      #pragma unroll
      for (int kb = 0; kb < 8; ++kb) {
        #pragma unroll
        for (int cc = 0; cc < 2; ++cc) {
          bf16x8 wf = *(const bf16x8*)&w1b[(wv * 32 + cc * 16 + l16) * WW + kb * 32 + lq * 8];
          acc[cc] = __builtin_amdgcn_mfma_f32_16x16x32_bf16(wf, af[kb], acc[cc], 0, 0, 0);
        }
      }
      #pragma unroll
      for (int cc = 0; cc < 2; ++cc) {
        bf16x4 o;
        #pragma unroll
        for (int r = 0; r < 4; ++r)
          o[r] = (__bf16)softplus_f(acc[cc][r] + b1r[cc][r]);
        *(bf16x4*)&g1s[l16 * PAD_G + wv * 32 + cc * 16 + lq * 4] = o;
      }
    }
    __syncthreads();   // 3: g1 ready

    // ---- gemm2: wave owns h = 8j+wv (cols c0+wv*64 .. +63), rows l16, all 64 d.
    //      c-outer / kb-inner, g1 frags hoisted: r3-gentle load pattern.
    {
      bf16x8 af[8];
      #pragma unroll
      for (int kb = 0; kb < 8; ++kb)
        af[kb] = *(const bf16x8*)&g1s[l16 * PAD_G + kb * 32 + lq * 8];
      f32x4 acc[4] = {};
      #pragma unroll
      for (int c = 0; c < 4; ++c) {
        #pragma unroll
        for (int kb = 0; kb < 8; ++kb) {
          bf16x8 wf = *(const bf16x8*)&w2b[(size_t)(c0 + wv * 64 + c * 16 + l16) * WW +
                                           kb * 32 + lq * 8];
          acc[c] = __builtin_amdgcn_mfma_f32_16x16x32_bf16(wf, af[kb], acc[c], 0, 0, 0);
        }
      }
      // lane: brow = l16, d = c*16 + lq*4 + r
      float pp = 0.f;
      #pragma unroll
      for (int c = 0; c < 4; ++c)
        #pragma unroll
        for (int r = 0; r < 4; ++r) {
          float f = tanh_f(acc[c][r] + b2r[c][r]);
          pp = fmaf(f, dvv[c][r], pp);
        }
      pp += __shfl_xor(pp, 16);
      pp += __shfl_xor(pp, 32);
      // direct publish from the wave (no pbuf, no barrier)
      if (l < 16) {
        yreg += pp;
        publish_y(dst, myidx, yreg, (uint32_t)(k + 2));
      }
    }
    // loop: WAR on yb/g0/g1 protected transitively by barriers 1-3 (see analysis)
  }

  if (l < 16) yA[myidx] = yreg;
}

__global__ __launch_bounds__(256) void final_kernel(const float* __restrict__ y,
                                                    const float* __restrict__ lw,
                                                    const float* __restrict__ lb,
                                                    float* __restrict__ out) {
  int b = threadIdx.x;
  float a = lb[0];
  for (int h = 0; h < HH; ++h) a = fmaf(y[b * HH + h], lw[h], a);
  out[b] = 1.f / (1.f + __expf(-a));
}

extern "C" void kernel_launch(void* const* d_in, const int* in_sizes, int n_in,
                              void* d_out, int out_size, void* d_ws, size_t ws_size,
                              hipStream_t stream) {
  const float* cdp = (const float*)d_in[1];
  const float* ccp = (const float*)d_in[2];
  const float* cbp = (const float*)d_in[3];
  const float* cap = (const float*)d_in[4];
  const float* iw0 = (const float*)d_in[5];
  const float* ib0 = (const float*)d_in[6];
  const float* iw1 = (const float*)d_in[7];
  const float* ib1 = (const float*)d_in[8];
  const float* iw2 = (const float*)d_in[9];
  const float* ib2 = (const float*)d_in[10];
  const float* fw0 = (const float*)d_in[11];
  const float* fb0 = (const float*)d_in[12];
  const float* fw1 = (const float*)d_in[13];
  const float* fb1 = (const float*)d_in[14];
  const float* fw2 = (const float*)d_in[15];
  const float* fb2 = (const float*)d_in[16];
  const float* lw  = (const float*)d_in[17];
  const float* lb  = (const float*)d_in[18];

  char* ws = (char*)d_ws;
  __bf16* w0b = (__bf16*)(ws);                              // 64 KB
  __bf16* w1b = (__bf16*)(ws + 65536);                      // 128 KB
  __bf16* w2b = (__bf16*)(ws + 65536 + 131072);             // 4 MB
  float* yA = (float*)(ws + 65536 + 131072 + 4194304);      // 128 KB
  uint32_t* pk = (uint32_t*)(ws + 65536 + 131072 + 4194304 + 131072);  // 256 KB (2 slots)

  hipMemsetAsync(pk, 0, 2 * BB * HH * sizeof(uint32_t), stream);
  prep_kernel<<<512, 256, 0, stream>>>(fw0, fw1, fw2, w0b, w1b, w2b);
  init_kernel<<<BB, 256, 0, stream>>>(cap, iw0, ib0, iw1, ib1, iw2, ib2, yA);
  step_persist<<<256, 512, 0, stream>>>(w0b, w1b, w2b, fb0, fb1, fb2,
                                        cbp, ccp, cdp, yA, pk);
  final_kernel<<<1, 256, 0, stream>>>(yA, lw, lb, (float*)d_out);

  (void)in_sizes; (void)n_in; (void)out_size; (void)ws_size;
}